// Round 1
// baseline (8665.216 us; speedup 1.0000x reference)
//
#include <hip/hip_runtime.h>
#include <math.h>

namespace {

constexpr int B = 4, T = 1024, C = 1024, H = 16, L = 2, E = 8, HD = 64;
constexpr int NTOK = B * T;          // 4096
constexpr int CAP = 1024;            // B*T*K/E
constexpr int C3 = 3 * C, C4 = 4 * C;

// ---------------- embedding ----------------
__global__ __launch_bounds__(256) void embed_kernel(const int* __restrict__ ids,
    const float* __restrict__ tok, const float* __restrict__ pos, float* __restrict__ x) {
  int idx = blockIdx.x * 256 + threadIdx.x;      // float4 index
  int n = idx >> 8;                              // token (C/4 = 256 float4 per row)
  int c4 = idx & 255;
  int t = n & (T - 1);
  int id = ids[n];
  float4 a = ((const float4*)(tok + (size_t)id * C))[c4];
  float4 p = ((const float4*)(pos + (size_t)t * C))[c4];
  float4 r{a.x + p.x, a.y + p.y, a.z + p.z, a.w + p.w};
  ((float4*)x)[idx] = r;
}

// ---------------- layernorm ----------------
__global__ __launch_bounds__(256) void ln_kernel(const float* __restrict__ in, float* __restrict__ out,
    const float* __restrict__ w, const float* __restrict__ b) {
  __shared__ float red[8];
  int row = blockIdx.x, tid = threadIdx.x;
  float4 v = ((const float4*)(in + (size_t)row * C))[tid];
  float s = v.x + v.y + v.z + v.w;
  #pragma unroll
  for (int off = 32; off > 0; off >>= 1) s += __shfl_down(s, off);
  if ((tid & 63) == 0) red[tid >> 6] = s;
  __syncthreads();
  float mean = (red[0] + red[1] + red[2] + red[3]) * (1.f / C);
  __syncthreads();
  float dx = v.x - mean, dy = v.y - mean, dz = v.z - mean, dw = v.w - mean;
  float sq = dx * dx + dy * dy + dz * dz + dw * dw;
  #pragma unroll
  for (int off = 32; off > 0; off >>= 1) sq += __shfl_down(sq, off);
  if ((tid & 63) == 0) red[tid >> 6] = sq;
  __syncthreads();
  float var = (red[0] + red[1] + red[2] + red[3]) * (1.f / C);
  float rs = rsqrtf(var + 1e-5f);
  float4 wc = ((const float4*)w)[tid];
  float4 bc = ((const float4*)b)[tid];
  float4 o{dx * rs * wc.x + bc.x, dy * rs * wc.y + bc.y,
           dz * rs * wc.z + bc.z, dw * rs * wc.w + bc.w};
  ((float4*)(out + (size_t)row * C))[tid] = o;
}

// ---------------- generic tiled GEMM: C[m][n] (+)= sum_k A[m][k]*Bm[n][k] (+bias) ----------------
template<bool GATHER, bool ACCUM, bool RELU, bool BIAS>
__global__ __launch_bounds__(256) void gemm_tn(
    const float* __restrict__ A, const float* __restrict__ Bm,
    const float* __restrict__ bias, float* __restrict__ Cm,
    const int* __restrict__ rowidx, const int* __restrict__ cnt,
    int M, int N, int Kd)
{
  __shared__ float As[16][68];
  __shared__ float Bs[16][68];
  int tid = threadIdx.x;
  int row0 = blockIdx.y * 64, col0 = blockIdx.x * 64;
  int Mr = M;
  if (cnt) { int cc = *cnt; Mr = cc < M ? cc : M; }
  if (row0 >= Mr) return;
  int tm = tid >> 4, tn = tid & 15;
  int lr = tid >> 2, lk = (tid & 3) << 2;
  int ar = row0 + lr;
  bool aok = ar < Mr;
  int arid = aok ? (GATHER ? rowidx[ar] : ar) : (GATHER ? rowidx[row0] : row0);
  const float* Ap = A + (size_t)arid * Kd + lk;
  const float* Bp = Bm + (size_t)(col0 + lr) * Kd + lk;
  float acc[4][4] = {};
  for (int k0 = 0; k0 < Kd; k0 += 16) {
    float4 av = aok ? *(const float4*)(Ap + k0) : float4{0.f, 0.f, 0.f, 0.f};
    float4 bv = *(const float4*)(Bp + k0);
    __syncthreads();
    As[lk + 0][lr] = av.x; As[lk + 1][lr] = av.y; As[lk + 2][lr] = av.z; As[lk + 3][lr] = av.w;
    Bs[lk + 0][lr] = bv.x; Bs[lk + 1][lr] = bv.y; Bs[lk + 2][lr] = bv.z; Bs[lk + 3][lr] = bv.w;
    __syncthreads();
    #pragma unroll
    for (int kk = 0; kk < 16; kk++) {
      float4 a4 = *(const float4*)&As[kk][tm << 2];
      float4 b4 = *(const float4*)&Bs[kk][tn << 2];
      float a0 = a4.x, a1 = a4.y, a2 = a4.z, a3 = a4.w;
      float b0 = b4.x, b1 = b4.y, b2 = b4.z, b3 = b4.w;
      acc[0][0] += a0 * b0; acc[0][1] += a0 * b1; acc[0][2] += a0 * b2; acc[0][3] += a0 * b3;
      acc[1][0] += a1 * b0; acc[1][1] += a1 * b1; acc[1][2] += a1 * b2; acc[1][3] += a1 * b3;
      acc[2][0] += a2 * b0; acc[2][1] += a2 * b1; acc[2][2] += a2 * b2; acc[2][3] += a2 * b3;
      acc[3][0] += a3 * b0; acc[3][1] += a3 * b1; acc[3][2] += a3 * b2; acc[3][3] += a3 * b3;
    }
  }
  int nbase = col0 + (tn << 2);
  float4 bb{0.f, 0.f, 0.f, 0.f};
  if constexpr (BIAS) bb = *(const float4*)(bias + nbase);
  #pragma unroll
  for (int i = 0; i < 4; i++) {
    int m = row0 + (tm << 2) + i;
    if (m >= Mr) continue;
    float4 r{acc[i][0] + bb.x, acc[i][1] + bb.y, acc[i][2] + bb.z, acc[i][3] + bb.w};
    if constexpr (RELU) {
      r.x = fmaxf(r.x, 0.f); r.y = fmaxf(r.y, 0.f); r.z = fmaxf(r.z, 0.f); r.w = fmaxf(r.w, 0.f);
    }
    float* cp = Cm + (size_t)m * N + nbase;
    if constexpr (ACCUM) {
      float4 old = *(const float4*)cp;
      r.x += old.x; r.y += old.y; r.z += old.z; r.w += old.w;
    }
    *(float4*)cp = r;
  }
}

// ---------------- flash attention (fp32) ----------------
__global__ __launch_bounds__(256) void attn_kernel(const float* __restrict__ qkv, float* __restrict__ ao) {
  constexpr int QT = 64, ST = 32;
  __shared__ float qs[QT][65];
  __shared__ float ks[ST][65];
  __shared__ float vs[ST][65];
  __shared__ float Sb[QT][33];
  __shared__ float fbuf[QT], lbuf[QT];
  int tid = threadIdx.x;
  int qt = blockIdx.x, bh = blockIdx.y;
  int b = bh >> 4, hh = bh & 15;
  {
    int r = tid >> 2, dq = (tid & 3) << 4;
    const float* src = qkv + (size_t)(b * T + qt * QT + r) * 3 * C + hh * HD + dq;
    #pragma unroll
    for (int i = 0; i < 4; i++) {
      float4 v = *(const float4*)(src + i * 4);
      qs[r][dq + i * 4 + 0] = v.x; qs[r][dq + i * 4 + 1] = v.y;
      qs[r][dq + i * 4 + 2] = v.z; qs[r][dq + i * 4 + 3] = v.w;
    }
  }
  float m = -INFINITY, l = 0.f;
  float o[16];
  #pragma unroll
  for (int i = 0; i < 16; i++) o[i] = 0.f;
  int qr = tid & 63, grp = tid >> 6;
  for (int s0 = 0; s0 < T; s0 += ST) {
    __syncthreads();
    {
      int r = tid >> 3, dq = (tid & 7) << 3;
      const float* kx = qkv + ((size_t)(b * T + s0 + r) * 3 + 1) * C + hh * HD + dq;
      float4 k0 = *(const float4*)kx, k1 = *(const float4*)(kx + 4);
      const float* vx = kx + C;
      float4 v0 = *(const float4*)vx, v1 = *(const float4*)(vx + 4);
      ks[r][dq + 0] = k0.x; ks[r][dq + 1] = k0.y; ks[r][dq + 2] = k0.z; ks[r][dq + 3] = k0.w;
      ks[r][dq + 4] = k1.x; ks[r][dq + 5] = k1.y; ks[r][dq + 6] = k1.z; ks[r][dq + 7] = k1.w;
      vs[r][dq + 0] = v0.x; vs[r][dq + 1] = v0.y; vs[r][dq + 2] = v0.z; vs[r][dq + 3] = v0.w;
      vs[r][dq + 4] = v1.x; vs[r][dq + 5] = v1.y; vs[r][dq + 6] = v1.z; vs[r][dq + 7] = v1.w;
    }
    __syncthreads();
    float sa[8];
    #pragma unroll
    for (int j = 0; j < 8; j++) sa[j] = 0.f;
    int sb0 = grp << 3;
    for (int d = 0; d < 64; d++) {
      float qd = qs[qr][d];
      #pragma unroll
      for (int j = 0; j < 8; j++) sa[j] += qd * ks[sb0 + j][d];
    }
    #pragma unroll
    for (int j = 0; j < 8; j++) Sb[qr][sb0 + j] = sa[j] * 0.125f;
    __syncthreads();
    if (tid < QT) {
      float tmax = -INFINITY;
      #pragma unroll
      for (int s = 0; s < ST; s++) tmax = fmaxf(tmax, Sb[tid][s]);
      float mn = fmaxf(m, tmax);
      float f = expf(m - mn);
      float ps = 0.f;
      for (int s = 0; s < ST; s++) {
        float p = expf(Sb[tid][s] - mn);
        Sb[tid][s] = p;
        ps += p;
      }
      l = l * f + ps;
      m = mn;
      fbuf[tid] = f;
    }
    __syncthreads();
    float f = fbuf[qr];
    int d0 = grp << 4;
    #pragma unroll
    for (int i = 0; i < 16; i++) o[i] *= f;
    for (int s = 0; s < ST; s++) {
      float p = Sb[qr][s];
      #pragma unroll
      for (int i = 0; i < 16; i++) o[i] += p * vs[s][d0 + i];
    }
  }
  __syncthreads();
  if (tid < QT) lbuf[tid] = 1.f / l;
  __syncthreads();
  float linv = lbuf[qr];
  float* dst = ao + (size_t)(b * T + qt * QT + qr) * C + hh * HD + (grp << 4);
  #pragma unroll
  for (int i = 0; i < 16; i += 4) {
    float4 v{o[i] * linv, o[i + 1] * linv, o[i + 2] * linv, o[i + 3] * linv};
    *(float4*)(dst + i) = v;
  }
}

// ---------------- router: logits, noisy top-2, gates ----------------
__global__ __launch_bounds__(64) void router_kernel(
    const float* __restrict__ xin, const float* __restrict__ rt_w, const float* __restrict__ rt_b,
    const float* __restrict__ nz_w, const float* __restrict__ nz_b, const float* __restrict__ noise,
    int* __restrict__ i0, int* __restrict__ i1, float* __restrict__ g0, float* __restrict__ g1)
{
  int n = blockIdx.x, lane = threadIdx.x;
  const float* xr = xin + (size_t)n * C;
  float acc[16];
  #pragma unroll
  for (int e = 0; e < 16; e++) acc[e] = 0.f;
  for (int c = lane; c < C; c += 64) {
    float xv = xr[c];
    #pragma unroll
    for (int e = 0; e < 8; e++) {
      acc[e]     += xv * rt_w[e * C + c];
      acc[8 + e] += xv * nz_w[e * C + c];
    }
  }
  #pragma unroll
  for (int e = 0; e < 16; e++) {
    #pragma unroll
    for (int off = 32; off > 0; off >>= 1) acc[e] += __shfl_down(acc[e], off);
  }
  if (lane == 0) {
    float nv[8];
    #pragma unroll
    for (int e = 0; e < 8; e++) {
      float lg = acc[e] + rt_b[e];
      float nl = acc[8 + e] + nz_b[e];
      float sp = fmaxf(nl, 0.f) + log1pf(expf(-fabsf(nl)));   // stable softplus
      nv[e] = lg + noise[(size_t)n * E + e] * sp;
    }
    float v0 = -INFINITY, v1 = -INFINITY; int b0 = -1, b1 = -1;
    #pragma unroll
    for (int e = 0; e < 8; e++) {
      float v = nv[e];
      if (v > v0)      { v1 = v0; b1 = b0; v0 = v; b0 = e; }
      else if (v > v1) { v1 = v; b1 = e; }
    }
    float ex = expf(v1 - v0);
    float inv = 1.f / (1.f + ex);
    i0[n] = b0; i1[n] = b1;
    g0[n] = inv; g1[n] = ex * inv;
  }
}

// ---------------- capacity assignment: wave e scans tokens in order ----------------
__global__ __launch_bounds__(512) void capacity_kernel(
    const int* __restrict__ i0, const int* __restrict__ i1,
    const float* __restrict__ g0, const float* __restrict__ g1,
    int* __restrict__ sel, float* __restrict__ gsel, int* __restrict__ counts)
{
  int e = threadIdx.x >> 6, lane = threadIdx.x & 63;
  int cnt = 0;
  unsigned long long ltmask = (lane == 0) ? 0ull : (~0ull >> (64 - lane));
  for (int base = 0; base < NTOK; base += 64) {
    int t = base + lane;
    int a = i0[t], bb = i1[t];
    bool match = (a == e) || (bb == e);
    unsigned long long mk = __ballot(match);
    int pos = cnt + __popcll(mk & ltmask);
    if (match && pos < CAP) {
      sel[e * CAP + pos] = t;
      gsel[e * CAP + pos] = (a == e) ? g0[t] : g1[t];
    }
    cnt += __popcll(mk);
  }
  if (lane == 0) counts[e] = cnt < CAP ? cnt : CAP;
}

// ---------------- scatter expert outputs back with gates ----------------
__global__ __launch_bounds__(256) void scatter_kernel(
    const float* __restrict__ eout, const int* __restrict__ sel,
    const float* __restrict__ gsel, const int* __restrict__ cnt, float* __restrict__ x)
{
  int idx = blockIdx.x * 256 + threadIdx.x;
  int j = idx >> 8;
  if (j >= *cnt) return;
  int c4 = idx & 255;
  int t = sel[j];
  float g = gsel[j];
  float4 v = ((const float4*)(eout + (size_t)j * C))[c4];
  float* xp = x + (size_t)t * C + (c4 << 2);
  float4 o = *(const float4*)xp;
  o.x += g * v.x; o.y += g * v.y; o.z += g * v.z; o.w += g * v.w;
  *(float4*)xp = o;
}

// ---------------- final: mean over T then head dot ----------------
__global__ __launch_bounds__(256) void head_kernel(const float* __restrict__ xin,
    const float* __restrict__ hw, const float* __restrict__ hb, float* __restrict__ out)
{
  __shared__ float red[8];
  int b = blockIdx.x, tid = threadIdx.x;
  float4 wv = ((const float4*)hw)[tid];
  float s = 0.f;
  for (int t = 0; t < T; t++) {
    float4 v = ((const float4*)(xin + (size_t)(b * T + t) * C))[tid];
    s += v.x * wv.x + v.y * wv.y + v.z * wv.z + v.w * wv.w;
  }
  #pragma unroll
  for (int off = 32; off > 0; off >>= 1) s += __shfl_down(s, off);
  if ((tid & 63) == 0) red[tid >> 6] = s;
  __syncthreads();
  if (tid == 0) out[b] = (red[0] + red[1] + red[2] + red[3]) * (1.f / T) + hb[0];
}

}  // namespace

extern "C" void kernel_launch(void* const* d_in, const int* in_sizes, int n_in,
                              void* d_out, int out_size, void* d_ws, size_t ws_size,
                              hipStream_t stream) {
  (void)in_sizes; (void)n_in; (void)out_size; (void)ws_size;
  const int*   ids     = (const int*)d_in[0];
  const float* noise   = (const float*)d_in[1];
  const float* tok_emb = (const float*)d_in[2];
  const float* pos_emb = (const float*)d_in[3];
  const float* ln1_w   = (const float*)d_in[4];
  const float* ln1_b   = (const float*)d_in[5];
  const float* qkv_w   = (const float*)d_in[6];
  const float* out_w   = (const float*)d_in[7];
  const float* ln2_w   = (const float*)d_in[8];
  const float* ln2_b   = (const float*)d_in[9];
  const float* rt_w    = (const float*)d_in[10];
  const float* rt_b    = (const float*)d_in[11];
  const float* nz_w    = (const float*)d_in[12];
  const float* nz_b    = (const float*)d_in[13];
  const float* e_w1    = (const float*)d_in[14];
  const float* e_b1    = (const float*)d_in[15];
  const float* e_w2    = (const float*)d_in[16];
  const float* e_b2    = (const float*)d_in[17];
  const float* lnf_w   = (const float*)d_in[18];
  const float* lnf_b   = (const float*)d_in[19];
  const float* head_w  = (const float*)d_in[20];
  const float* head_b  = (const float*)d_in[21];
  float* out = (float*)d_out;

  char* wsp = (char*)d_ws;
  size_t off = 0;
  auto alloc = [&](size_t n) { char* p = wsp + off; off += (n + 255) & ~(size_t)255; return p; };
  float* x    = (float*)alloc((size_t)NTOK * C * 4);
  float* t1   = (float*)alloc((size_t)NTOK * C * 4);
  float* qkvb = (float*)alloc((size_t)NTOK * C3 * 4);
  float* ao   = (float*)alloc((size_t)NTOK * C * 4);
  float* hbuf = (float*)alloc((size_t)CAP * C4 * 4);
  float* eo   = (float*)alloc((size_t)CAP * C * 4);
  int*   i0   = (int*)alloc(NTOK * 4);
  int*   i1   = (int*)alloc(NTOK * 4);
  float* g0   = (float*)alloc(NTOK * 4);
  float* g1   = (float*)alloc(NTOK * 4);
  int*   sel  = (int*)alloc(E * CAP * 4);
  float* gsel = (float*)alloc(E * CAP * 4);
  int*   counts = (int*)alloc(E * 4);

  embed_kernel<<<NTOK * C / 4 / 256, 256, 0, stream>>>(ids, tok_emb, pos_emb, x);

  for (int l = 0; l < L; l++) {
    // attention block
    ln_kernel<<<NTOK, 256, 0, stream>>>(x, t1, ln1_w + l * C, ln1_b + l * C);
    gemm_tn<false, false, false, false><<<dim3(C3 / 64, NTOK / 64), 256, 0, stream>>>(
        t1, qkv_w + (size_t)l * C3 * C, nullptr, qkvb, nullptr, nullptr, NTOK, C3, C);
    attn_kernel<<<dim3(T / 64, B * H), 256, 0, stream>>>(qkvb, ao);
    gemm_tn<false, true, false, false><<<dim3(C / 64, NTOK / 64), 256, 0, stream>>>(
        ao, out_w + (size_t)l * C * C, nullptr, x, nullptr, nullptr, NTOK, C, C);

    // MoE block
    ln_kernel<<<NTOK, 256, 0, stream>>>(x, t1, ln2_w + l * C, ln2_b + l * C);
    router_kernel<<<NTOK, 64, 0, stream>>>(t1, rt_w + (size_t)l * E * C, rt_b + l * E,
        nz_w + (size_t)l * E * C, nz_b + l * E, noise + (size_t)l * NTOK * E, i0, i1, g0, g1);
    capacity_kernel<<<1, 512, 0, stream>>>(i0, i1, g0, g1, sel, gsel, counts);
    for (int e = 0; e < E; e++) {
      const float* w1 = e_w1 + (size_t)(l * E + e) * C4 * C;
      const float* b1 = e_b1 + (size_t)(l * E + e) * C4;
      const float* w2 = e_w2 + (size_t)(l * E + e) * C * C4;
      const float* b2 = e_b2 + (size_t)(l * E + e) * C;
      gemm_tn<true, false, true, true><<<dim3(C4 / 64, CAP / 64), 256, 0, stream>>>(
          t1, w1, b1, hbuf, sel + e * CAP, counts + e, CAP, C4, C);
      gemm_tn<false, false, false, true><<<dim3(C / 64, CAP / 64), 256, 0, stream>>>(
          hbuf, w2, b2, eo, nullptr, counts + e, CAP, C, C4);
      scatter_kernel<<<CAP * C / 4 / 256, 256, 0, stream>>>(eo, sel + e * CAP, gsel + e * CAP,
                                                            counts + e, x);
    }
  }

  ln_kernel<<<NTOK, 256, 0, stream>>>(x, t1, lnf_w, lnf_b);
  head_kernel<<<B, 256, 0, stream>>>(t1, head_w, head_b, out);
}

// Round 2
// 3000.663 us; speedup vs baseline: 2.8878x; 2.8878x over previous
//
#include <hip/hip_runtime.h>
#include <hip/hip_bf16.h>
#include <math.h>

namespace {

constexpr int B = 4, T = 1024, C = 1024, H = 16, L = 2, E = 8, HD = 64;
constexpr int NTOK = B * T;          // 4096
constexpr int CAP = 1024;            // B*T*K/E
constexpr int C3 = 3 * C, C4 = 4 * C;

typedef __attribute__((ext_vector_type(8))) short bf16x8;
typedef __attribute__((ext_vector_type(4))) float f32x4;

static __device__ inline short f2b(float f) {
  __hip_bfloat16 h = __float2bfloat16(f);
  return *reinterpret_cast<short*>(&h);
}
static __device__ inline bf16x8 pack8(float4 a, float4 b) {
  bf16x8 r;
  r[0] = f2b(a.x); r[1] = f2b(a.y); r[2] = f2b(a.z); r[3] = f2b(a.w);
  r[4] = f2b(b.x); r[5] = f2b(b.y); r[6] = f2b(b.z); r[7] = f2b(b.w);
  return r;
}

// swizzled byte offset within a tile of 128-byte rows
#define SWZ(row, kb) (((row) << 7) + ((kb) ^ (((row) & 7) << 4)))

// ---------------- embedding ----------------
__global__ __launch_bounds__(256) void embed_kernel(const int* __restrict__ ids,
    const float* __restrict__ tok, const float* __restrict__ pos, float* __restrict__ x) {
  int idx = blockIdx.x * 256 + threadIdx.x;
  int n = idx >> 8;
  int c4 = idx & 255;
  int t = n & (T - 1);
  int id = ids[n];
  float4 a = ((const float4*)(tok + (size_t)id * C))[c4];
  float4 p = ((const float4*)(pos + (size_t)t * C))[c4];
  float4 r{a.x + p.x, a.y + p.y, a.z + p.z, a.w + p.w};
  ((float4*)x)[idx] = r;
}

// ---------------- layernorm ----------------
__global__ __launch_bounds__(256) void ln_kernel(const float* __restrict__ in, float* __restrict__ out,
    const float* __restrict__ w, const float* __restrict__ b) {
  __shared__ float red[8];
  int row = blockIdx.x, tid = threadIdx.x;
  float4 v = ((const float4*)(in + (size_t)row * C))[tid];
  float s = v.x + v.y + v.z + v.w;
  #pragma unroll
  for (int off = 32; off > 0; off >>= 1) s += __shfl_down(s, off);
  if ((tid & 63) == 0) red[tid >> 6] = s;
  __syncthreads();
  float mean = (red[0] + red[1] + red[2] + red[3]) * (1.f / C);
  __syncthreads();
  float dx = v.x - mean, dy = v.y - mean, dz = v.z - mean, dw = v.w - mean;
  float sq = dx * dx + dy * dy + dz * dz + dw * dw;
  #pragma unroll
  for (int off = 32; off > 0; off >>= 1) sq += __shfl_down(sq, off);
  if ((tid & 63) == 0) red[tid >> 6] = sq;
  __syncthreads();
  float var = (red[0] + red[1] + red[2] + red[3]) * (1.f / C);
  float rs = rsqrtf(var + 1e-5f);
  float4 wc = ((const float4*)w)[tid];
  float4 bc = ((const float4*)b)[tid];
  float4 o{dx * rs * wc.x + bc.x, dy * rs * wc.y + bc.y,
           dz * rs * wc.z + bc.z, dw * rs * wc.w + bc.w};
  ((float4*)(out + (size_t)row * C))[tid] = o;
}

// ---------------- MFMA GEMM: C[m][n] op= sum_k A[m][k]*W[n][k] (+bias, relu, gated scatter) ----
// BM=BN=128, BK=64, 256 threads = 4 waves (2x2), per-wave 64x64 via 4x4 16x16x32 MFMA frags.
template<bool GATHER, bool ACCUM, bool RELU, bool BIAS, bool SCATTER>
__global__ __launch_bounds__(256) void gemm_mfma(
    const float* __restrict__ A, const float* __restrict__ W,
    const float* __restrict__ bias, float* __restrict__ Cout,
    const int* __restrict__ rowidx, const float* __restrict__ rowscale,
    const int* __restrict__ cnt, int M, int N, int Kd)
{
  int Mr = M;
  if (cnt) { int cc = *cnt; Mr = cc < M ? cc : M; }
  int row0 = blockIdx.y * 128, col0 = blockIdx.x * 128;
  if (row0 >= Mr) return;

  __shared__ alignas(16) char smem[32768];     // As 16KB | Bs 16KB
  char* Ab = smem;
  char* Bb = smem + 16384;

  int t = threadIdx.x;
  int w = t >> 6, lane = t & 63, lm = lane & 15, lg = lane >> 4;
  int wr = w >> 1, wc = w & 1;

  // staging assignment: thread t covers rows (t>>2) and (t>>2)+64, 16 floats at k0=(t&3)*16
  int srow = t >> 2;
  int k0 = (t & 3) * 16;
  int ar0 = row0 + srow, ar1 = row0 + srow + 64;
  int ia0, ia1;
  if constexpr (GATHER) {
    ia0 = rowidx[ar0 < Mr ? ar0 : Mr - 1];
    ia1 = rowidx[ar1 < Mr ? ar1 : Mr - 1];
  } else { ia0 = ar0; ia1 = ar1; }
  const float* apA0 = A + (size_t)ia0 * Kd + k0;
  const float* apA1 = A + (size_t)ia1 * Kd + k0;
  const float* apB0 = W + (size_t)(col0 + srow) * Kd + k0;
  const float* apB1 = apB0 + (size_t)64 * Kd;

  float4 pa[2][4], pb[2][4];
  auto LOAD = [&](int kt) {
    const float* a0 = apA0 + kt * 64;
    const float* a1 = apA1 + kt * 64;
    const float* b0 = apB0 + kt * 64;
    const float* b1 = apB1 + kt * 64;
    #pragma unroll
    for (int i = 0; i < 4; i++) {
      pa[0][i] = ((const float4*)a0)[i];
      pa[1][i] = ((const float4*)a1)[i];
      pb[0][i] = ((const float4*)b0)[i];
      pb[1][i] = ((const float4*)b1)[i];
    }
  };

  f32x4 acc[4][4];
  #pragma unroll
  for (int i = 0; i < 4; i++)
    #pragma unroll
    for (int j = 0; j < 4; j++) acc[i][j] = f32x4{0.f, 0.f, 0.f, 0.f};

  int NT = Kd >> 6;
  LOAD(0);
  for (int kt = 0; kt < NT; kt++) {
    __syncthreads();
    {
      int kb0 = k0 * 2;        // byte col base: (t&3)*32
      #pragma unroll
      for (int h = 0; h < 2; h++) {
        int r = srow + 64 * h;
        *(bf16x8*)(Ab + SWZ(r, kb0))      = pack8(pa[h][0], pa[h][1]);
        *(bf16x8*)(Ab + SWZ(r, kb0 + 16)) = pack8(pa[h][2], pa[h][3]);
        *(bf16x8*)(Bb + SWZ(r, kb0))      = pack8(pb[h][0], pb[h][1]);
        *(bf16x8*)(Bb + SWZ(r, kb0 + 16)) = pack8(pb[h][2], pb[h][3]);
      }
    }
    __syncthreads();
    if (kt + 1 < NT) LOAD(kt + 1);
    #pragma unroll
    for (int ks = 0; ks < 2; ks++) {
      bf16x8 af[4], bf[4];
      #pragma unroll
      for (int mi = 0; mi < 4; mi++)
        af[mi] = *(const bf16x8*)(Ab + SWZ(wr * 64 + mi * 16 + lm, ks * 64 + lg * 16));
      #pragma unroll
      for (int ni = 0; ni < 4; ni++)
        bf[ni] = *(const bf16x8*)(Bb + SWZ(wc * 64 + ni * 16 + lm, ks * 64 + lg * 16));
      #pragma unroll
      for (int mi = 0; mi < 4; mi++)
        #pragma unroll
        for (int ni = 0; ni < 4; ni++)
          acc[mi][ni] = __builtin_amdgcn_mfma_f32_16x16x32_bf16(af[mi], bf[ni], acc[mi][ni], 0, 0, 0);
    }
  }

  // epilogue
  float cbias[4];
  #pragma unroll
  for (int ni = 0; ni < 4; ni++)
    cbias[ni] = BIAS ? bias[col0 + wc * 64 + ni * 16 + lm] : 0.f;
  #pragma unroll
  for (int mi = 0; mi < 4; mi++) {
    #pragma unroll
    for (int rr = 0; rr < 4; rr++) {
      int m = row0 + wr * 64 + mi * 16 + lg * 4 + rr;
      if (m >= Mr) continue;
      int orow = m;
      float scale = 1.f;
      if constexpr (SCATTER) { orow = rowidx[m]; scale = rowscale[m]; }
      float* cp = Cout + (size_t)orow * N + col0 + wc * 64 + lm;
      #pragma unroll
      for (int ni = 0; ni < 4; ni++) {
        float v = acc[mi][ni][rr] + cbias[ni];
        if constexpr (RELU) v = fmaxf(v, 0.f);
        float* p = cp + ni * 16;
        if constexpr (SCATTER)      *p += scale * v;
        else if constexpr (ACCUM)   *p += v;
        else                        *p = v;
      }
    }
  }
}

// ---------------- MFMA flash attention ----------------
// grid (T/64, B*H); 256 threads = 4 waves; wave w owns q rows [w*16, w*16+16)
__global__ __launch_bounds__(256) void attn_mfma(const float* __restrict__ qkv, float* __restrict__ ao) {
  __shared__ alignas(16) char smem[20480];   // Ks 4KB | Vt 8KB | P 4x2KB
  char* Ks = smem;
  char* Vt = smem + 4096;
  char* Pb = smem + 12288;

  int t = threadIdx.x, w = t >> 6, lane = t & 63, lm = lane & 15, lg = lane >> 4;
  int qt = blockIdx.x, bh = blockIdx.y, b = bh >> 4, h = bh & 15;
  const float* base = qkv + (size_t)b * T * C3;

  // Q fragments, pre-scaled by 1/sqrt(HD)
  bf16x8 qf[2];
  {
    int qrow = qt * 64 + w * 16 + lm;
    const float* qp = base + (size_t)qrow * C3 + h * HD + lg * 8;
    #pragma unroll
    for (int kf = 0; kf < 2; kf++) {
      float4 x0 = *(const float4*)(qp + kf * 32);
      float4 x1 = *(const float4*)(qp + kf * 32 + 4);
      x0.x *= 0.125f; x0.y *= 0.125f; x0.z *= 0.125f; x0.w *= 0.125f;
      x1.x *= 0.125f; x1.y *= 0.125f; x1.z *= 0.125f; x1.w *= 0.125f;
      qf[kf] = pack8(x0, x1);
    }
  }

  f32x4 o[4];
  #pragma unroll
  for (int i = 0; i < 4; i++) o[i] = f32x4{0.f, 0.f, 0.f, 0.f};
  float mrun[4] = {-INFINITY, -INFINITY, -INFINITY, -INFINITY};
  float lrun[4] = {0.f, 0.f, 0.f, 0.f};

  // staging: K: thread covers row s=(t>>3), d=(t&7)*8..+8 (two float4)
  //          V: thread covers row s=(t>>3), d = (t&7) + 8i (strided, conflict-free b16 writes)
  int ksrow = t >> 3, kd0 = (t & 7) * 8;
  int vdl = t & 7;
  float4 kv0, kv1;
  float vv[8];
  auto LOADKV = [&](int s0) {
    const float* kp = base + (size_t)(s0 + ksrow) * C3 + C + h * HD + kd0;
    kv0 = *(const float4*)kp;
    kv1 = *(const float4*)(kp + 4);
    const float* vp = base + (size_t)(s0 + ksrow) * C3 + 2 * C + h * HD + vdl;
    #pragma unroll
    for (int i = 0; i < 8; i++) vv[i] = vp[8 * i];
  };

  LOADKV(0);
  for (int s0 = 0; s0 < T; s0 += 32) {
    __syncthreads();
    // stage K (one b128) and V transposed (8 scalar b16, lanes spread by vdl)
    *(bf16x8*)(Ks + SWZ(ksrow, kd0 * 2)) = pack8(kv0, kv1);
    #pragma unroll
    for (int i = 0; i < 8; i++) {
      int d = 8 * i + vdl;
      *(short*)(Vt + (d << 7) + ((ksrow * 2) ^ ((d & 7) << 4))) = f2b(vv[i]);
    }
    __syncthreads();
    if (s0 + 32 < T) LOADKV(s0 + 32);

    // S = Q K^T  (two 16-col s-subtiles)
    f32x4 sacc[2];
    sacc[0] = f32x4{0.f, 0.f, 0.f, 0.f};
    sacc[1] = f32x4{0.f, 0.f, 0.f, 0.f};
    #pragma unroll
    for (int ni = 0; ni < 2; ni++)
      #pragma unroll
      for (int ks = 0; ks < 2; ks++) {
        bf16x8 kfrag = *(const bf16x8*)(Ks + SWZ(ni * 16 + lm, ks * 64 + lg * 16));
        sacc[ni] = __builtin_amdgcn_mfma_f32_16x16x32_bf16(qf[ks], kfrag, sacc[ni], 0, 0, 0);
      }

    // online softmax (rows q = lg*4+r, cols = 16 lanes x 2 subtiles)
    float pv[8], fr[4];
    #pragma unroll
    for (int r = 0; r < 4; r++) {
      float s0v = sacc[0][r], s1v = sacc[1][r];
      float tmax = fmaxf(s0v, s1v);
      #pragma unroll
      for (int mk = 1; mk < 16; mk <<= 1) tmax = fmaxf(tmax, __shfl_xor(tmax, mk));
      float mn = fmaxf(mrun[r], tmax);
      float f = __expf(mrun[r] - mn);
      float p0 = __expf(s0v - mn), p1 = __expf(s1v - mn);
      float ps = p0 + p1;
      #pragma unroll
      for (int mk = 1; mk < 16; mk <<= 1) ps += __shfl_xor(ps, mk);
      lrun[r] = lrun[r] * f + ps;
      mrun[r] = mn;
      fr[r] = f;
      pv[r] = p0; pv[4 + r] = p1;
    }

    // write P (bf16) to per-wave LDS, rescale O, then PV MFMAs
    char* P = Pb + w * 2048;
    #pragma unroll
    for (int ni = 0; ni < 2; ni++)
      #pragma unroll
      for (int r = 0; r < 4; r++) {
        int q = lg * 4 + r;
        int kbyte = (ni * 16 + lm) * 2;
        *(short*)(P + (q << 7) + (kbyte ^ ((q & 7) << 4))) = f2b(pv[ni * 4 + r]);
      }
    #pragma unroll
    for (int ni = 0; ni < 4; ni++) {
      o[ni][0] *= fr[0]; o[ni][1] *= fr[1]; o[ni][2] *= fr[2]; o[ni][3] *= fr[3];
    }
    bf16x8 pfrag = *(const bf16x8*)(P + SWZ(lm, lg * 16));
    #pragma unroll
    for (int ni = 0; ni < 4; ni++) {
      bf16x8 vfrag = *(const bf16x8*)(Vt + SWZ(ni * 16 + lm, lg * 16));
      o[ni] = __builtin_amdgcn_mfma_f32_16x16x32_bf16(pfrag, vfrag, o[ni], 0, 0, 0);
    }
  }

  // epilogue
  float inv[4];
  #pragma unroll
  for (int r = 0; r < 4; r++) inv[r] = 1.f / lrun[r];
  #pragma unroll
  for (int r = 0; r < 4; r++) {
    int qrow = qt * 64 + w * 16 + lg * 4 + r;
    float* dst = ao + (size_t)(b * T + qrow) * C + h * HD + lm;
    #pragma unroll
    for (int ni = 0; ni < 4; ni++) dst[ni * 16] = o[ni][r] * inv[r];
  }
}

// ---------------- router ----------------
__global__ __launch_bounds__(64) void router_kernel(
    const float* __restrict__ xin, const float* __restrict__ rt_w, const float* __restrict__ rt_b,
    const float* __restrict__ nz_w, const float* __restrict__ nz_b, const float* __restrict__ noise,
    int* __restrict__ i0, int* __restrict__ i1, float* __restrict__ g0, float* __restrict__ g1)
{
  int n = blockIdx.x, lane = threadIdx.x;
  const float* xr = xin + (size_t)n * C;
  float acc[16];
  #pragma unroll
  for (int e = 0; e < 16; e++) acc[e] = 0.f;
  for (int c = lane; c < C; c += 64) {
    float xv = xr[c];
    #pragma unroll
    for (int e = 0; e < 8; e++) {
      acc[e]     += xv * rt_w[e * C + c];
      acc[8 + e] += xv * nz_w[e * C + c];
    }
  }
  #pragma unroll
  for (int e = 0; e < 16; e++) {
    #pragma unroll
    for (int off = 32; off > 0; off >>= 1) acc[e] += __shfl_down(acc[e], off);
  }
  if (lane == 0) {
    float nv[8];
    #pragma unroll
    for (int e = 0; e < 8; e++) {
      float lg = acc[e] + rt_b[e];
      float nl = acc[8 + e] + nz_b[e];
      float sp = fmaxf(nl, 0.f) + log1pf(expf(-fabsf(nl)));
      nv[e] = lg + noise[(size_t)n * E + e] * sp;
    }
    float v0 = -INFINITY, v1 = -INFINITY; int b0 = -1, b1 = -1;
    #pragma unroll
    for (int e = 0; e < 8; e++) {
      float v = nv[e];
      if (v > v0)      { v1 = v0; b1 = b0; v0 = v; b0 = e; }
      else if (v > v1) { v1 = v; b1 = e; }
    }
    float ex = expf(v1 - v0);
    float inv = 1.f / (1.f + ex);
    i0[n] = b0; i1[n] = b1;
    g0[n] = inv; g1[n] = ex * inv;
  }
}

// ---------------- capacity assignment ----------------
__global__ __launch_bounds__(512) void capacity_kernel(
    const int* __restrict__ i0, const int* __restrict__ i1,
    const float* __restrict__ g0, const float* __restrict__ g1,
    int* __restrict__ sel, float* __restrict__ gsel, int* __restrict__ counts)
{
  int e = threadIdx.x >> 6, lane = threadIdx.x & 63;
  int cnt = 0;
  unsigned long long ltmask = (lane == 0) ? 0ull : (~0ull >> (64 - lane));
  for (int basei = 0; basei < NTOK; basei += 64) {
    int tt = basei + lane;
    int a = i0[tt], bb = i1[tt];
    bool match = (a == e) || (bb == e);
    unsigned long long mk = __ballot(match);
    int pos = cnt + __popcll(mk & ltmask);
    if (match && pos < CAP) {
      sel[e * CAP + pos] = tt;
      gsel[e * CAP + pos] = (a == e) ? g0[tt] : g1[tt];
    }
    cnt += __popcll(mk);
  }
  if (lane == 0) counts[e] = cnt < CAP ? cnt : CAP;
}

// ---------------- final head ----------------
__global__ __launch_bounds__(256) void head_kernel(const float* __restrict__ xin,
    const float* __restrict__ hw, const float* __restrict__ hb, float* __restrict__ out)
{
  __shared__ float red[8];
  int b = blockIdx.x, tid = threadIdx.x;
  float4 wv = ((const float4*)hw)[tid];
  float s = 0.f;
  for (int t = 0; t < T; t++) {
    float4 v = ((const float4*)(xin + (size_t)(b * T + t) * C))[tid];
    s += v.x * wv.x + v.y * wv.y + v.z * wv.z + v.w * wv.w;
  }
  #pragma unroll
  for (int off = 32; off > 0; off >>= 1) s += __shfl_down(s, off);
  if ((tid & 63) == 0) red[tid >> 6] = s;
  __syncthreads();
  if (tid == 0) out[b] = (red[0] + red[1] + red[2] + red[3]) * (1.f / T) + hb[0];
}

}  // namespace

extern "C" void kernel_launch(void* const* d_in, const int* in_sizes, int n_in,
                              void* d_out, int out_size, void* d_ws, size_t ws_size,
                              hipStream_t stream) {
  (void)in_sizes; (void)n_in; (void)out_size; (void)ws_size;
  const int*   ids     = (const int*)d_in[0];
  const float* noise   = (const float*)d_in[1];
  const float* tok_emb = (const float*)d_in[2];
  const float* pos_emb = (const float*)d_in[3];
  const float* ln1_w   = (const float*)d_in[4];
  const float* ln1_b   = (const float*)d_in[5];
  const float* qkv_w   = (const float*)d_in[6];
  const float* out_w   = (const float*)d_in[7];
  const float* ln2_w   = (const float*)d_in[8];
  const float* ln2_b   = (const float*)d_in[9];
  const float* rt_w    = (const float*)d_in[10];
  const float* rt_b    = (const float*)d_in[11];
  const float* nz_w    = (const float*)d_in[12];
  const float* nz_b    = (const float*)d_in[13];
  const float* e_w1    = (const float*)d_in[14];
  const float* e_b1    = (const float*)d_in[15];
  const float* e_w2    = (const float*)d_in[16];
  const float* e_b2    = (const float*)d_in[17];
  const float* lnf_w   = (const float*)d_in[18];
  const float* lnf_b   = (const float*)d_in[19];
  const float* head_w  = (const float*)d_in[20];
  const float* head_b  = (const float*)d_in[21];
  float* out = (float*)d_out;

  char* wsp = (char*)d_ws;
  size_t off = 0;
  auto alloc = [&](size_t n) { char* p = wsp + off; off += (n + 255) & ~(size_t)255; return p; };
  float* x    = (float*)alloc((size_t)NTOK * C * 4);
  float* t1   = (float*)alloc((size_t)NTOK * C * 4);
  float* qkvb = (float*)alloc((size_t)NTOK * C3 * 4);
  float* ao   = (float*)alloc((size_t)NTOK * C * 4);
  float* hbuf = (float*)alloc((size_t)CAP * C4 * 4);
  int*   i0   = (int*)alloc(NTOK * 4);
  int*   i1   = (int*)alloc(NTOK * 4);
  float* g0   = (float*)alloc(NTOK * 4);
  float* g1   = (float*)alloc(NTOK * 4);
  int*   sel  = (int*)alloc(E * CAP * 4);
  float* gsel = (float*)alloc(E * CAP * 4);
  int*   counts = (int*)alloc(E * 4);

  embed_kernel<<<NTOK * C / 4 / 256, 256, 0, stream>>>(ids, tok_emb, pos_emb, x);

  for (int l = 0; l < L; l++) {
    // attention block
    ln_kernel<<<NTOK, 256, 0, stream>>>(x, t1, ln1_w + l * C, ln1_b + l * C);
    gemm_mfma<false, false, false, false, false><<<dim3(C3 / 128, NTOK / 128), 256, 0, stream>>>(
        t1, qkv_w + (size_t)l * C3 * C, nullptr, qkvb, nullptr, nullptr, nullptr, NTOK, C3, C);
    attn_mfma<<<dim3(T / 64, B * H), 256, 0, stream>>>(qkvb, ao);
    gemm_mfma<false, true, false, false, false><<<dim3(C / 128, NTOK / 128), 256, 0, stream>>>(
        ao, out_w + (size_t)l * C * C, nullptr, x, nullptr, nullptr, nullptr, NTOK, C, C);

    // MoE block
    ln_kernel<<<NTOK, 256, 0, stream>>>(x, t1, ln2_w + l * C, ln2_b + l * C);
    router_kernel<<<NTOK, 64, 0, stream>>>(t1, rt_w + (size_t)l * E * C, rt_b + l * E,
        nz_w + (size_t)l * E * C, nz_b + l * E, noise + (size_t)l * NTOK * E, i0, i1, g0, g1);
    capacity_kernel<<<1, 512, 0, stream>>>(i0, i1, g0, g1, sel, gsel, counts);
    for (int e = 0; e < E; e++) {
      const float* w1 = e_w1 + (size_t)(l * E + e) * C4 * C;
      const float* b1 = e_b1 + (size_t)(l * E + e) * C4;
      const float* w2 = e_w2 + (size_t)(l * E + e) * C * C4;
      const float* b2 = e_b2 + (size_t)(l * E + e) * C;
      // FFN1: gather rows of t1 via sel, relu(x@w1^T + b1) -> hbuf
      gemm_mfma<true, false, true, true, false><<<dim3(C4 / 128, CAP / 128), 256, 0, stream>>>(
          t1, w1, b1, hbuf, sel + e * CAP, nullptr, counts + e, CAP, C4, C);
      // FFN2: hbuf@w2^T + b2, scattered into x with gate scaling
      gemm_mfma<false, false, false, true, true><<<dim3(C / 128, CAP / 128), 256, 0, stream>>>(
          hbuf, w2, b2, x, sel + e * CAP, gsel + e * CAP, counts + e, CAP, C, C4);
    }
  }

  ln_kernel<<<NTOK, 256, 0, stream>>>(x, t1, lnf_w, lnf_b);
  head_kernel<<<B, 256, 0, stream>>>(t1, head_w, head_b, out);
}

// Round 3
// 1103.936 us; speedup vs baseline: 7.8494x; 2.7182x over previous
//
#include <hip/hip_runtime.h>
#include <hip/hip_bf16.h>
#include <math.h>

namespace {

constexpr int B = 4, T = 1024, C = 1024, Hh = 16, L = 2, E = 8, HD = 64;
constexpr int NTOK = B * T;          // 4096
constexpr int CAP = 1024;            // B*T*K/E
constexpr int C3 = 3 * C, C4 = 4 * C;

typedef __attribute__((ext_vector_type(8))) short bf16x8;
typedef __attribute__((ext_vector_type(4))) float f32x4;

static __device__ __forceinline__ short f2b(float f) {
  __hip_bfloat16 h = __float2bfloat16(f);
  return *reinterpret_cast<short*>(&h);
}

// swizzled byte offset within a tile of 128-byte rows
#define SWZ(row, kb) (((row) << 7) + ((kb) ^ (((row) & 7) << 4)))

static __device__ __forceinline__ void gload16(const void* g, void* l) {
  __builtin_amdgcn_global_load_lds((const __attribute__((address_space(1))) void*)g,
                                   (__attribute__((address_space(3))) void*)l, 16, 0, 0);
}

// ---------------- fp32 -> bf16 bulk convert ----------------
__global__ __launch_bounds__(256) void cvt_kernel(const float* __restrict__ in,
    unsigned short* __restrict__ out, size_t n) {
  size_t i = ((size_t)blockIdx.x * 256 + threadIdx.x) * 4;
  size_t stride = (size_t)gridDim.x * 1024;
  for (; i < n; i += stride) {
    float4 v = *(const float4*)(in + i);
    short4 r{f2b(v.x), f2b(v.y), f2b(v.z), f2b(v.w)};
    *(short4*)(out + i) = r;
  }
}

// ---------------- embedding ----------------
__global__ __launch_bounds__(256) void embed_kernel(const int* __restrict__ ids,
    const float* __restrict__ tok, const float* __restrict__ pos, float* __restrict__ x) {
  int idx = blockIdx.x * 256 + threadIdx.x;
  int n = idx >> 8;
  int c4 = idx & 255;
  int t = n & (T - 1);
  int id = ids[n];
  float4 a = ((const float4*)(tok + (size_t)id * C))[c4];
  float4 p = ((const float4*)(pos + (size_t)t * C))[c4];
  float4 r{a.x + p.x, a.y + p.y, a.z + p.z, a.w + p.w};
  ((float4*)x)[idx] = r;
}

// ---------------- layernorm: fp32 in -> fp32 + bf16 out ----------------
__global__ __launch_bounds__(256) void ln_kernel(const float* __restrict__ in,
    float* __restrict__ out, unsigned short* __restrict__ outb,
    const float* __restrict__ w, const float* __restrict__ b) {
  __shared__ float red[8];
  int row = blockIdx.x, tid = threadIdx.x;
  float4 v = ((const float4*)(in + (size_t)row * C))[tid];
  float s = v.x + v.y + v.z + v.w;
  #pragma unroll
  for (int off = 32; off > 0; off >>= 1) s += __shfl_down(s, off);
  if ((tid & 63) == 0) red[tid >> 6] = s;
  __syncthreads();
  float mean = (red[0] + red[1] + red[2] + red[3]) * (1.f / C);
  __syncthreads();
  float dx = v.x - mean, dy = v.y - mean, dz = v.z - mean, dw = v.w - mean;
  float sq = dx * dx + dy * dy + dz * dz + dw * dw;
  #pragma unroll
  for (int off = 32; off > 0; off >>= 1) sq += __shfl_down(sq, off);
  if ((tid & 63) == 0) red[tid >> 6] = sq;
  __syncthreads();
  float var = (red[0] + red[1] + red[2] + red[3]) * (1.f / C);
  float rs = rsqrtf(var + 1e-5f);
  float4 wc = ((const float4*)w)[tid];
  float4 bc = ((const float4*)b)[tid];
  float4 o{dx * rs * wc.x + bc.x, dy * rs * wc.y + bc.y,
           dz * rs * wc.z + bc.z, dw * rs * wc.w + bc.w};
  ((float4*)(out + (size_t)row * C))[tid] = o;
  short4 ob{f2b(o.x), f2b(o.y), f2b(o.z), f2b(o.w)};
  *(short4*)(outb + (size_t)row * C + tid * 4) = ob;
}

// ---------------- bf16 MFMA GEMM, global_load_lds staging, grouped over blockIdx.z ------
// C[m][n] = sum_k A[m][k] * W[n][k]; BM=BN=128, BK=64; 256 threads = 4 waves (2x2).
// OUTMODE: 0 = store bf16, 1 = fp32 accumulate (residual), 2 = fp32 gated atomic scatter
template<bool GATHER, int OUTMODE, bool RELU, bool BIAS>
__global__ __launch_bounds__(256) void gemm_bf(
    const unsigned short* __restrict__ A, const unsigned short* __restrict__ W,
    const float* __restrict__ bias, void* __restrict__ CoutV,
    const int* __restrict__ rowidx, const float* __restrict__ rowscale,
    const int* __restrict__ cnts, int M, int N, int Kd,
    size_t strideA, size_t strideW, size_t strideOut, int strideBias, int strideIdx)
{
  int e = blockIdx.z;
  int Mr = M;
  if (cnts) { int cc = cnts[e]; Mr = cc < M ? cc : M; }
  int row0 = blockIdx.y * 128, col0 = blockIdx.x * 128;
  if (row0 >= Mr) return;

  __shared__ alignas(16) char smem[32768];   // A 16KB | B 16KB, [128][64] bf16 each
  char* Ab = smem;
  char* Bb = smem + 16384;

  const unsigned short* Ap = A + (size_t)e * strideA;
  const unsigned short* Wp = W + (size_t)e * strideW;
  const int* ridx = rowidx ? rowidx + (size_t)e * strideIdx : nullptr;

  int t = threadIdx.x, w = t >> 6, l = t & 63;
  int lm = l & 15, lg = l >> 4;
  int wr = w >> 1, wc = w & 1;

  // staging: wave w stages segments w*4+i; lane l -> row seg*8 + (l>>3), 16B at col (l&7)*16.
  // source col is XOR-swizzled so that swizzled ds_reads below are conflict-free.
  int lrow8 = l >> 3;
  int scol = ((l & 7) ^ lrow8) << 4;
  const char* srcA[4];
  const char* srcB[4];
  #pragma unroll
  for (int i = 0; i < 4; i++) {
    int seg = w * 4 + i;
    int rloc = seg * 8 + lrow8;
    int ag;
    if constexpr (GATHER) {
      int ar = row0 + rloc;
      if (ar >= Mr) ar = Mr - 1;
      ag = ridx[ar];
    } else {
      ag = row0 + rloc;
    }
    srcA[i] = (const char*)Ap + (size_t)ag * Kd * 2 + scol;
    srcB[i] = (const char*)Wp + (size_t)(col0 + rloc) * Kd * 2 + scol;
  }

  f32x4 acc[4][4];
  #pragma unroll
  for (int i = 0; i < 4; i++)
    #pragma unroll
    for (int j = 0; j < 4; j++) acc[i][j] = f32x4{0.f, 0.f, 0.f, 0.f};

  int NT = Kd >> 6;
  for (int kt = 0; kt < NT; kt++) {
    __syncthreads();
    #pragma unroll
    for (int i = 0; i < 4; i++) {
      int seg = w * 4 + i;
      gload16(srcA[i], Ab + seg * 1024);
      gload16(srcB[i], Bb + seg * 1024);
      srcA[i] += 128;
      srcB[i] += 128;
    }
    __syncthreads();
    #pragma unroll
    for (int ks = 0; ks < 2; ks++) {
      bf16x8 af[4], bfr[4];
      #pragma unroll
      for (int mi = 0; mi < 4; mi++)
        af[mi] = *(const bf16x8*)(Ab + SWZ(wr * 64 + mi * 16 + lm, ks * 64 + lg * 16));
      #pragma unroll
      for (int ni = 0; ni < 4; ni++)
        bfr[ni] = *(const bf16x8*)(Bb + SWZ(wc * 64 + ni * 16 + lm, ks * 64 + lg * 16));
      #pragma unroll
      for (int mi = 0; mi < 4; mi++)
        #pragma unroll
        for (int ni = 0; ni < 4; ni++)
          acc[mi][ni] = __builtin_amdgcn_mfma_f32_16x16x32_bf16(af[mi], bfr[ni], acc[mi][ni], 0, 0, 0);
    }
  }

  // epilogue
  float cbias[4];
  #pragma unroll
  for (int ni = 0; ni < 4; ni++)
    cbias[ni] = BIAS ? bias[(size_t)e * strideBias + col0 + wc * 64 + ni * 16 + lm] : 0.f;

  #pragma unroll
  for (int mi = 0; mi < 4; mi++) {
    #pragma unroll
    for (int rr = 0; rr < 4; rr++) {
      int m = row0 + wr * 64 + mi * 16 + lg * 4 + rr;
      if (m >= Mr) continue;
      int colb = col0 + wc * 64 + lm;
      #pragma unroll
      for (int ni = 0; ni < 4; ni++) {
        float v = acc[mi][ni][rr] + cbias[ni];
        if constexpr (RELU) v = fmaxf(v, 0.f);
        int col = colb + ni * 16;
        if constexpr (OUTMODE == 0) {
          unsigned short* Co = (unsigned short*)CoutV + (size_t)e * strideOut;
          Co[(size_t)m * N + col] = (unsigned short)f2b(v);
        } else if constexpr (OUTMODE == 1) {
          float* Co = (float*)CoutV;
          Co[(size_t)m * N + col] += v;
        } else {
          float* Co = (float*)CoutV;
          int orow = ridx[m];
          float sc = rowscale[(size_t)e * strideIdx + m];
          atomicAdd(&Co[(size_t)orow * N + col], sc * v);
        }
      }
    }
  }
}

// ---------------- MFMA flash attention (bf16 I/O) ----------------
// grid (T/64, B*H); 256 threads = 4 waves; wave w owns q rows [w*16, w*16+16)
__global__ __launch_bounds__(256) void attn_mfma(const unsigned short* __restrict__ qkv,
                                                 unsigned short* __restrict__ ao) {
  __shared__ alignas(16) char smem[20480];   // Ks 4KB | Vt 8KB | P 4x2KB
  char* Ks = smem;
  char* Vt = smem + 4096;
  char* Pb = smem + 12288;

  int t = threadIdx.x, w = t >> 6, lane = t & 63, lm = lane & 15, lg = lane >> 4;
  int qt = blockIdx.x, bh = blockIdx.y, b = bh >> 4, h = bh & 15;
  const unsigned short* base = qkv + (size_t)b * T * C3;

  // Q fragments (bf16 direct)
  bf16x8 qf[2];
  {
    int qrow = qt * 64 + w * 16 + lm;
    const unsigned short* qp = base + (size_t)qrow * C3 + h * HD + lg * 8;
    qf[0] = *(const bf16x8*)qp;
    qf[1] = *(const bf16x8*)(qp + 32);
  }

  f32x4 o[4];
  #pragma unroll
  for (int i = 0; i < 4; i++) o[i] = f32x4{0.f, 0.f, 0.f, 0.f};
  float mrun[4] = {-INFINITY, -INFINITY, -INFINITY, -INFINITY};
  float lrun[4] = {0.f, 0.f, 0.f, 0.f};

  int ksrow = t >> 3, kc = (t & 7) * 8;   // K: row, elem col
  int vdl = t & 7;                        // V: d-lane
  bf16x8 kreg;
  unsigned short vv[8];
  auto LOADKV = [&](int s0) {
    kreg = *(const bf16x8*)(base + (size_t)(s0 + ksrow) * C3 + C + h * HD + kc);
    const unsigned short* vp = base + (size_t)(s0 + ksrow) * C3 + 2 * C + h * HD + vdl;
    #pragma unroll
    for (int i = 0; i < 8; i++) vv[i] = vp[8 * i];
  };

  LOADKV(0);
  for (int s0 = 0; s0 < T; s0 += 32) {
    __syncthreads();
    *(bf16x8*)(Ks + SWZ(ksrow, kc * 2)) = kreg;
    #pragma unroll
    for (int i = 0; i < 8; i++) {
      int d = 8 * i + vdl;
      *(short*)(Vt + (d << 7) + ((ksrow * 2) ^ ((d & 7) << 4))) = (short)vv[i];
    }
    __syncthreads();
    if (s0 + 32 < T) LOADKV(s0 + 32);

    // S = Q K^T
    f32x4 sacc[2];
    sacc[0] = f32x4{0.f, 0.f, 0.f, 0.f};
    sacc[1] = f32x4{0.f, 0.f, 0.f, 0.f};
    #pragma unroll
    for (int ni = 0; ni < 2; ni++)
      #pragma unroll
      for (int ks = 0; ks < 2; ks++) {
        bf16x8 kfrag = *(const bf16x8*)(Ks + SWZ(ni * 16 + lm, ks * 64 + lg * 16));
        sacc[ni] = __builtin_amdgcn_mfma_f32_16x16x32_bf16(qf[ks], kfrag, sacc[ni], 0, 0, 0);
      }

    // online softmax (scale by 1/sqrt(HD) here)
    float pv[8], fr[4];
    #pragma unroll
    for (int r = 0; r < 4; r++) {
      float s0v = sacc[0][r] * 0.125f, s1v = sacc[1][r] * 0.125f;
      float tmax = fmaxf(s0v, s1v);
      #pragma unroll
      for (int mk = 1; mk < 16; mk <<= 1) tmax = fmaxf(tmax, __shfl_xor(tmax, mk));
      float mn = fmaxf(mrun[r], tmax);
      float f = __expf(mrun[r] - mn);
      float p0 = __expf(s0v - mn), p1 = __expf(s1v - mn);
      float ps = p0 + p1;
      #pragma unroll
      for (int mk = 1; mk < 16; mk <<= 1) ps += __shfl_xor(ps, mk);
      lrun[r] = lrun[r] * f + ps;
      mrun[r] = mn;
      fr[r] = f;
      pv[r] = p0; pv[4 + r] = p1;
    }

    char* P = Pb + w * 2048;
    #pragma unroll
    for (int ni = 0; ni < 2; ni++)
      #pragma unroll
      for (int r = 0; r < 4; r++) {
        int q = lg * 4 + r;
        int kbyte = (ni * 16 + lm) * 2;
        *(short*)(P + (q << 7) + (kbyte ^ ((q & 7) << 4))) = f2b(pv[ni * 4 + r]);
      }
    #pragma unroll
    for (int ni = 0; ni < 4; ni++) {
      o[ni][0] *= fr[0]; o[ni][1] *= fr[1]; o[ni][2] *= fr[2]; o[ni][3] *= fr[3];
    }
    bf16x8 pfrag = *(const bf16x8*)(P + SWZ(lm, lg * 16));
    #pragma unroll
    for (int ni = 0; ni < 4; ni++) {
      bf16x8 vfrag = *(const bf16x8*)(Vt + SWZ(ni * 16 + lm, lg * 16));
      o[ni] = __builtin_amdgcn_mfma_f32_16x16x32_bf16(pfrag, vfrag, o[ni], 0, 0, 0);
    }
  }

  float inv[4];
  #pragma unroll
  for (int r = 0; r < 4; r++) inv[r] = 1.f / lrun[r];
  #pragma unroll
  for (int r = 0; r < 4; r++) {
    int qrow = qt * 64 + w * 16 + lg * 4 + r;
    unsigned short* dst = ao + (size_t)(b * T + qrow) * C + h * HD + lm;
    #pragma unroll
    for (int ni = 0; ni < 4; ni++) dst[ni * 16] = (unsigned short)f2b(o[ni][r] * inv[r]);
  }
}

// ---------------- router ----------------
__global__ __launch_bounds__(64) void router_kernel(
    const float* __restrict__ xin, const float* __restrict__ rt_w, const float* __restrict__ rt_b,
    const float* __restrict__ nz_w, const float* __restrict__ nz_b, const float* __restrict__ noise,
    int* __restrict__ i0, int* __restrict__ i1, float* __restrict__ g0, float* __restrict__ g1)
{
  int n = blockIdx.x, lane = threadIdx.x;
  const float* xr = xin + (size_t)n * C;
  float acc[16];
  #pragma unroll
  for (int e = 0; e < 16; e++) acc[e] = 0.f;
  for (int c = lane; c < C; c += 64) {
    float xv = xr[c];
    #pragma unroll
    for (int e = 0; e < 8; e++) {
      acc[e]     += xv * rt_w[e * C + c];
      acc[8 + e] += xv * nz_w[e * C + c];
    }
  }
  #pragma unroll
  for (int e = 0; e < 16; e++) {
    #pragma unroll
    for (int off = 32; off > 0; off >>= 1) acc[e] += __shfl_down(acc[e], off);
  }
  if (lane == 0) {
    float nv[8];
    #pragma unroll
    for (int e = 0; e < 8; e++) {
      float lgt = acc[e] + rt_b[e];
      float nl = acc[8 + e] + nz_b[e];
      float sp = fmaxf(nl, 0.f) + log1pf(expf(-fabsf(nl)));
      nv[e] = lgt + noise[(size_t)n * E + e] * sp;
    }
    float v0 = -INFINITY, v1 = -INFINITY; int b0 = -1, b1 = -1;
    #pragma unroll
    for (int e = 0; e < 8; e++) {
      float v = nv[e];
      if (v > v0)      { v1 = v0; b1 = b0; v0 = v; b0 = e; }
      else if (v > v1) { v1 = v; b1 = e; }
    }
    float ex = expf(v1 - v0);
    float inv = 1.f / (1.f + ex);
    i0[n] = b0; i1[n] = b1;
    g0[n] = inv; g1[n] = ex * inv;
  }
}

// ---------------- capacity assignment ----------------
__global__ __launch_bounds__(512) void capacity_kernel(
    const int* __restrict__ i0, const int* __restrict__ i1,
    const float* __restrict__ g0, const float* __restrict__ g1,
    int* __restrict__ sel, float* __restrict__ gsel, int* __restrict__ counts)
{
  int e = threadIdx.x >> 6, lane = threadIdx.x & 63;
  int cnt = 0;
  unsigned long long ltmask = (lane == 0) ? 0ull : (~0ull >> (64 - lane));
  for (int basei = 0; basei < NTOK; basei += 64) {
    int tt = basei + lane;
    int a = i0[tt], bb = i1[tt];
    bool match = (a == e) || (bb == e);
    unsigned long long mk = __ballot(match);
    int pos = cnt + __popcll(mk & ltmask);
    if (match && pos < CAP) {
      sel[e * CAP + pos] = tt;
      gsel[e * CAP + pos] = (a == e) ? g0[tt] : g1[tt];
    }
    cnt += __popcll(mk);
  }
  if (lane == 0) counts[e] = cnt < CAP ? cnt : CAP;
}

// ---------------- final head ----------------
__global__ __launch_bounds__(256) void head_kernel(const float* __restrict__ xin,
    const float* __restrict__ hw, const float* __restrict__ hb, float* __restrict__ out)
{
  __shared__ float red[8];
  int b = blockIdx.x, tid = threadIdx.x;
  float4 wv = ((const float4*)hw)[tid];
  float s = 0.f;
  for (int t = 0; t < T; t++) {
    float4 v = ((const float4*)(xin + (size_t)(b * T + t) * C))[tid];
    s += v.x * wv.x + v.y * wv.y + v.z * wv.z + v.w * wv.w;
  }
  #pragma unroll
  for (int off = 32; off > 0; off >>= 1) s += __shfl_down(s, off);
  if ((tid & 63) == 0) red[tid >> 6] = s;
  __syncthreads();
  if (tid == 0) out[b] = (red[0] + red[1] + red[2] + red[3]) * (1.f / T) + hb[0];
}

}  // namespace

extern "C" void kernel_launch(void* const* d_in, const int* in_sizes, int n_in,
                              void* d_out, int out_size, void* d_ws, size_t ws_size,
                              hipStream_t stream) {
  (void)in_sizes; (void)n_in; (void)out_size; (void)ws_size;
  const int*   ids     = (const int*)d_in[0];
  const float* noise   = (const float*)d_in[1];
  const float* tok_emb = (const float*)d_in[2];
  const float* pos_emb = (const float*)d_in[3];
  const float* ln1_w   = (const float*)d_in[4];
  const float* ln1_b   = (const float*)d_in[5];
  const float* qkv_w   = (const float*)d_in[6];
  const float* out_w   = (const float*)d_in[7];
  const float* ln2_w   = (const float*)d_in[8];
  const float* ln2_b   = (const float*)d_in[9];
  const float* rt_w    = (const float*)d_in[10];
  const float* rt_b    = (const float*)d_in[11];
  const float* nz_w    = (const float*)d_in[12];
  const float* nz_b    = (const float*)d_in[13];
  const float* e_w1    = (const float*)d_in[14];
  const float* e_b1    = (const float*)d_in[15];
  const float* e_w2    = (const float*)d_in[16];
  const float* e_b2    = (const float*)d_in[17];
  const float* lnf_w   = (const float*)d_in[18];
  const float* lnf_b   = (const float*)d_in[19];
  const float* head_w  = (const float*)d_in[20];
  const float* head_b  = (const float*)d_in[21];
  float* out = (float*)d_out;

  char* wsp = (char*)d_ws;
  size_t off = 0;
  auto alloc = [&](size_t n) { char* p = wsp + off; off += (n + 255) & ~(size_t)255; return p; };
  float* x    = (float*)alloc((size_t)NTOK * C * 4);
  float* t1   = (float*)alloc((size_t)NTOK * C * 4);
  unsigned short* t1b    = (unsigned short*)alloc((size_t)NTOK * C * 2);
  unsigned short* qkvb   = (unsigned short*)alloc((size_t)NTOK * C3 * 2);
  unsigned short* aob    = (unsigned short*)alloc((size_t)NTOK * C * 2);
  unsigned short* hbuf   = (unsigned short*)alloc((size_t)E * CAP * C4 * 2);
  unsigned short* qkvw_b = (unsigned short*)alloc((size_t)L * C3 * C * 2);
  unsigned short* outw_b = (unsigned short*)alloc((size_t)L * C * C * 2);
  unsigned short* ew1_b  = (unsigned short*)alloc((size_t)L * E * C4 * C * 2);
  unsigned short* ew2_b  = (unsigned short*)alloc((size_t)L * E * C * C4 * 2);
  int*   i0   = (int*)alloc(NTOK * 4);
  int*   i1   = (int*)alloc(NTOK * 4);
  float* g0   = (float*)alloc(NTOK * 4);
  float* g1   = (float*)alloc(NTOK * 4);
  int*   sel  = (int*)alloc(E * CAP * 4);
  float* gsel = (float*)alloc(E * CAP * 4);
  int*   counts = (int*)alloc(E * 4);

  // weight conversions (once per launch)
  cvt_kernel<<<2048, 256, 0, stream>>>(qkv_w, qkvw_b, (size_t)L * C3 * C);
  cvt_kernel<<<2048, 256, 0, stream>>>(out_w, outw_b, (size_t)L * C * C);
  cvt_kernel<<<2048, 256, 0, stream>>>(e_w1, ew1_b, (size_t)L * E * C4 * C);
  cvt_kernel<<<2048, 256, 0, stream>>>(e_w2, ew2_b, (size_t)L * E * C * C4);

  embed_kernel<<<NTOK * C / 4 / 256, 256, 0, stream>>>(ids, tok_emb, pos_emb, x);

  for (int l = 0; l < L; l++) {
    // attention block
    ln_kernel<<<NTOK, 256, 0, stream>>>(x, t1, t1b, ln1_w + l * C, ln1_b + l * C);
    gemm_bf<false, 0, false, false><<<dim3(C3 / 128, NTOK / 128, 1), 256, 0, stream>>>(
        t1b, qkvw_b + (size_t)l * C3 * C, nullptr, qkvb,
        nullptr, nullptr, nullptr, NTOK, C3, C, 0, 0, 0, 0, 0);
    attn_mfma<<<dim3(T / 64, B * Hh), 256, 0, stream>>>(qkvb, aob);
    gemm_bf<false, 1, false, false><<<dim3(C / 128, NTOK / 128, 1), 256, 0, stream>>>(
        aob, outw_b + (size_t)l * C * C, nullptr, x,
        nullptr, nullptr, nullptr, NTOK, C, C, 0, 0, 0, 0, 0);

    // MoE block
    ln_kernel<<<NTOK, 256, 0, stream>>>(x, t1, t1b, ln2_w + l * C, ln2_b + l * C);
    router_kernel<<<NTOK, 64, 0, stream>>>(t1, rt_w + (size_t)l * E * C, rt_b + l * E,
        nz_w + (size_t)l * E * C, nz_b + l * E, noise + (size_t)l * NTOK * E, i0, i1, g0, g1);
    capacity_kernel<<<1, 512, 0, stream>>>(i0, i1, g0, g1, sel, gsel, counts);

    // grouped FFN1 over all experts: hbuf[e] = relu(gather(t1b, sel[e]) @ w1[e]^T + b1[e])
    gemm_bf<true, 0, true, true><<<dim3(C4 / 128, CAP / 128, E), 256, 0, stream>>>(
        t1b, ew1_b + (size_t)l * E * C4 * C, e_b1 + (size_t)l * E * C4, hbuf,
        sel, nullptr, counts, CAP, C4, C,
        0, (size_t)C4 * C, (size_t)CAP * C4, C4, CAP);
    // grouped FFN2: x[sel[e][m]] += gsel[e][m] * (hbuf[e] @ w2[e]^T + b2[e])
    gemm_bf<false, 2, false, true><<<dim3(C / 128, CAP / 128, E), 256, 0, stream>>>(
        hbuf, ew2_b + (size_t)l * E * C * C4, e_b2 + (size_t)l * E * C, x,
        sel, gsel, counts, CAP, C, C4,
        (size_t)CAP * C4, (size_t)C * C4, 0, C, CAP);
  }

  ln_kernel<<<NTOK, 256, 0, stream>>>(x, t1, t1b, lnf_w, lnf_b);
  head_kernel<<<B, 256, 0, stream>>>(t1, head_w, head_b, out);
}